// Round 1
// baseline (291.732 us; speedup 1.0000x reference)
//
#include <hip/hip_runtime.h>
#include <math.h>

#define F 1024
#define BM 128
#define BN 128
#define BK 16

// ---------------- LayerNorm: one block per row, row lives in registers ----------------
__global__ __launch_bounds__(256) void ln_kernel(const float* __restrict__ x,
                                                 const float* __restrict__ gamma,
                                                 const float* __restrict__ beta,
                                                 float* __restrict__ xn) {
  const int row = blockIdx.x;
  const int tid = threadIdx.x;
  const float4 v = ((const float4*)(x + (size_t)row * F))[tid];
  float s = v.x + v.y + v.z + v.w;
#pragma unroll
  for (int off = 32; off > 0; off >>= 1) s += __shfl_down(s, off, 64);
  __shared__ float red[4];
  __shared__ float red2[4];
  const int lane = tid & 63, wv = tid >> 6;
  if (lane == 0) red[wv] = s;
  __syncthreads();
  const float mu = (red[0] + red[1] + red[2] + red[3]) * (1.0f / F);
  const float dx = v.x - mu, dy = v.y - mu, dz = v.z - mu, dw = v.w - mu;
  float sq = dx * dx + dy * dy + dz * dz + dw * dw;
#pragma unroll
  for (int off = 32; off > 0; off >>= 1) sq += __shfl_down(sq, off, 64);
  if (lane == 0) red2[wv] = sq;
  __syncthreads();
  const float var = (red2[0] + red2[1] + red2[2] + red2[3]) * (1.0f / F);
  const float r = rsqrtf(var + 1e-5f);
  const float4 g = ((const float4*)gamma)[tid];
  const float4 bb = ((const float4*)beta)[tid];
  float4 o;
  o.x = dx * r * g.x + bb.x;
  o.y = dy * r * g.y + bb.y;
  o.z = dz * r * g.z + bb.z;
  o.w = dw * r * g.w + bb.w;
  ((float4*)(xn + (size_t)row * F))[tid] = o;
}

// ---------------- Tropical (max,+) GEMM: out[m,n] = max_k A[m,k]+W[k,n], then max(bias) ----
__global__ __launch_bounds__(256) void trop_kernel(const float* __restrict__ A,
                                                   const float* __restrict__ Wm,
                                                   const float* __restrict__ bias,
                                                   float* __restrict__ out) {
  __shared__ float As[BK][BM + 4];  // A stored transposed: As[k][m]; +4 pad keeps 16B align
  __shared__ float Bs[BK][BN];

  const int tid = threadIdx.x;
  const int tx = tid & 15;   // 16 col-groups of 8
  const int ty = tid >> 4;   // 16 row-groups of 8
  const int row0 = blockIdx.y * BM;
  const int col0 = blockIdx.x * BN;

  // A-tile staging: 128 rows x 16 k = 512 float4 along k; 2 per thread
  const int am = tid >> 2;          // 0..63 (row within tile), second load +64
  const int ak = (tid & 3) << 2;    // k offset 0,4,8,12
  // B-tile staging: 16 k-rows x 128 cols = 512 float4 along n; 2 per thread
  const int bk = tid >> 5;          // 0..7, second load +8
  const int bn = (tid & 31) << 2;   // col offset 0..124

  const float* Arow0 = A + (size_t)(row0 + am) * F + ak;
  const float* Arow1 = A + (size_t)(row0 + am + 64) * F + ak;
  const float* Wrow0 = Wm + (size_t)bk * F + col0 + bn;
  const float* Wrow1 = Wm + (size_t)(bk + 8) * F + col0 + bn;

  float acc[8][8];
#pragma unroll
  for (int m = 0; m < 8; ++m)
#pragma unroll
    for (int n = 0; n < 8; ++n) acc[m][n] = -INFINITY;

  // prefetch tile 0 into registers
  float4 a0s = *(const float4*)(Arow0);
  float4 a1s = *(const float4*)(Arow1);
  float4 b0s = *(const float4*)(Wrow0);
  float4 b1s = *(const float4*)(Wrow1);

  const int NT = F / BK;  // 64
  for (int kt = 0; kt < NT; ++kt) {
    // commit staged registers to LDS
    As[ak + 0][am] = a0s.x;
    As[ak + 1][am] = a0s.y;
    As[ak + 2][am] = a0s.z;
    As[ak + 3][am] = a0s.w;
    As[ak + 0][am + 64] = a1s.x;
    As[ak + 1][am + 64] = a1s.y;
    As[ak + 2][am + 64] = a1s.z;
    As[ak + 3][am + 64] = a1s.w;
    *(float4*)&Bs[bk][bn] = b0s;
    *(float4*)&Bs[bk + 8][bn] = b1s;
    __syncthreads();

    // prefetch next tile from global while computing this one
    if (kt + 1 < NT) {
      const int k0 = (kt + 1) * BK;
      a0s = *(const float4*)(Arow0 + k0);
      a1s = *(const float4*)(Arow1 + k0);
      b0s = *(const float4*)(Wrow0 + (size_t)k0 * F);
      b1s = *(const float4*)(Wrow1 + (size_t)k0 * F);
    }

#pragma unroll
    for (int k = 0; k < BK; k += 2) {
      float a0[8], a1[8], b0[8], b1[8];
      *(float4*)&a0[0] = *(const float4*)&As[k][ty * 8];
      *(float4*)&a0[4] = *(const float4*)&As[k][ty * 8 + 4];
      *(float4*)&a1[0] = *(const float4*)&As[k + 1][ty * 8];
      *(float4*)&a1[4] = *(const float4*)&As[k + 1][ty * 8 + 4];
      *(float4*)&b0[0] = *(const float4*)&Bs[k][tx * 8];
      *(float4*)&b0[4] = *(const float4*)&Bs[k][tx * 8 + 4];
      *(float4*)&b1[0] = *(const float4*)&Bs[k + 1][tx * 8];
      *(float4*)&b1[4] = *(const float4*)&Bs[k + 1][tx * 8 + 4];
#pragma unroll
      for (int m = 0; m < 8; ++m)
#pragma unroll
        for (int n = 0; n < 8; ++n)
          // fmaxf(fmaxf(x,y),z) -> v_max3_f32: 3 VALU ops per 2 k-steps
          acc[m][n] = fmaxf(fmaxf(acc[m][n], a0[m] + b0[n]), a1[m] + b1[n]);
    }
    __syncthreads();
  }

  // epilogue: out = max(acc, bias[n])
  const float4 bv0 = *(const float4*)(bias + col0 + tx * 8);
  const float4 bv1 = *(const float4*)(bias + col0 + tx * 8 + 4);
#pragma unroll
  for (int m = 0; m < 8; ++m) {
    float* orow = out + (size_t)(row0 + ty * 8 + m) * F + col0 + tx * 8;
    float4 o0, o1;
    o0.x = fmaxf(acc[m][0], bv0.x);
    o0.y = fmaxf(acc[m][1], bv0.y);
    o0.z = fmaxf(acc[m][2], bv0.z);
    o0.w = fmaxf(acc[m][3], bv0.w);
    o1.x = fmaxf(acc[m][4], bv1.x);
    o1.y = fmaxf(acc[m][5], bv1.y);
    o1.z = fmaxf(acc[m][6], bv1.z);
    o1.w = fmaxf(acc[m][7], bv1.w);
    *(float4*)orow = o0;
    *(float4*)(orow + 4) = o1;
  }
}

extern "C" void kernel_launch(void* const* d_in, const int* in_sizes, int n_in,
                              void* d_out, int out_size, void* d_ws, size_t ws_size,
                              hipStream_t stream) {
  const float* x = (const float*)d_in[0];
  const float* Wm = (const float*)d_in[1];
  const float* bias = (const float*)d_in[2];
  const float* gamma = (const float*)d_in[3];
  const float* beta = (const float*)d_in[4];
  float* out = (float*)d_out;
  float* xn = (float*)d_ws;  // [B, F] f32 = 16 MB scratch

  const int Brows = in_sizes[0] / F;  // 4096

  ln_kernel<<<Brows, 256, 0, stream>>>(x, gamma, beta, xn);

  dim3 grid(F / BN, Brows / BM);  // 8 x 32 = 256 blocks
  trop_kernel<<<grid, 256, 0, stream>>>(xn, Wm, bias, out);
}

// Round 2
// 261.311 us; speedup vs baseline: 1.1164x; 1.1164x over previous
//
#include <hip/hip_runtime.h>
#include <math.h>

#define F 1024
#define BM 128
#define BN 128
#define BK 16

typedef float v2f __attribute__((ext_vector_type(2)));

// ---------------- LayerNorm: one WAVE per row, no __syncthreads ----------------
__global__ __launch_bounds__(256) void ln_kernel(const float* __restrict__ x,
                                                 const float* __restrict__ gamma,
                                                 const float* __restrict__ beta,
                                                 float* __restrict__ xn) {
  const int lane = threadIdx.x & 63;
  const int wv = threadIdx.x >> 6;
  const int row = blockIdx.x * 4 + wv;
  const float4* xr = (const float4*)(x + (size_t)row * F);
  float4 v[4];
  float s = 0.f;
#pragma unroll
  for (int j = 0; j < 4; ++j) {
    v[j] = xr[lane + 64 * j];
    s += v[j].x + v[j].y + v[j].z + v[j].w;
  }
#pragma unroll
  for (int off = 32; off; off >>= 1) s += __shfl_xor(s, off, 64);
  const float mu = s * (1.0f / F);
  float sq = 0.f;
#pragma unroll
  for (int j = 0; j < 4; ++j) {
    v[j].x -= mu; v[j].y -= mu; v[j].z -= mu; v[j].w -= mu;
    sq += v[j].x * v[j].x + v[j].y * v[j].y + v[j].z * v[j].z + v[j].w * v[j].w;
  }
#pragma unroll
  for (int off = 32; off; off >>= 1) sq += __shfl_xor(sq, off, 64);
  const float r = rsqrtf(sq * (1.0f / F) + 1e-5f);
  const float4* g4 = (const float4*)gamma;
  const float4* b4 = (const float4*)beta;
  float4* o = (float4*)(xn + (size_t)row * F);
#pragma unroll
  for (int j = 0; j < 4; ++j) {
    const int idx = lane + 64 * j;
    const float4 g = g4[idx];
    const float4 bb = b4[idx];
    float4 ov;
    ov.x = v[j].x * r * g.x + bb.x;
    ov.y = v[j].y * r * g.y + bb.y;
    ov.z = v[j].z * r * g.z + bb.z;
    ov.w = v[j].w * r * g.w + bb.w;
    o[idx] = ov;
  }
}

// ---------------- Tropical (max,+) GEMM ----------------
// out[m,n] = max(max_k A[m,k]+W[k,n], bias[n])
// Thread (tx,ty): rows 8ty..8ty+7, cols {4tx..4tx+3} u {64+4tx..64+4tx+3}
// (column split keeps Bs b128 reads at 2-way bank aliasing = free)
__global__ __launch_bounds__(256) void trop_kernel(const float* __restrict__ A,
                                                   const float* __restrict__ Wm,
                                                   const float* __restrict__ bias,
                                                   float* __restrict__ out) {
  __shared__ float As[BK][BM + 4];  // transposed: As[k][m]
  __shared__ float Bs[BK][BN];

  const int tid = threadIdx.x;
  const int tx = tid & 15;
  const int ty = tid >> 4;
  const int row0 = blockIdx.y * BM;
  const int col0 = blockIdx.x * BN;

  // A staging: thread -> (row am / am+64, k = ak..ak+3)
  const int am = tid >> 2;
  const int ak = (tid & 3) << 2;
  // B staging: thread -> (k-row bk / bk+8, cols bn..bn+3)
  const int bk = tid >> 5;
  const int bn = (tid & 31) << 2;

  const float* Arow0 = A + (size_t)(row0 + am) * F + ak;
  const float* Arow1 = A + (size_t)(row0 + am + 64) * F + ak;
  const float* Wrow0 = Wm + (size_t)bk * F + col0 + bn;
  const float* Wrow1 = Wm + (size_t)(bk + 8) * F + col0 + bn;

  v2f acc[8][4];
#pragma unroll
  for (int m = 0; m < 8; ++m)
#pragma unroll
    for (int q = 0; q < 4; ++q) acc[m][q] = (v2f)(-INFINITY);

  // prefetch tile 0 into registers
  float4 a0s = *(const float4*)(Arow0);
  float4 a1s = *(const float4*)(Arow1);
  float4 b0s = *(const float4*)(Wrow0);
  float4 b1s = *(const float4*)(Wrow1);

  const int NT = F / BK;  // 64
  for (int kt = 0; kt < NT; ++kt) {
    As[ak + 0][am] = a0s.x;
    As[ak + 1][am] = a0s.y;
    As[ak + 2][am] = a0s.z;
    As[ak + 3][am] = a0s.w;
    As[ak + 0][am + 64] = a1s.x;
    As[ak + 1][am + 64] = a1s.y;
    As[ak + 2][am + 64] = a1s.z;
    As[ak + 3][am + 64] = a1s.w;
    *(float4*)&Bs[bk][bn] = b0s;
    *(float4*)&Bs[bk + 8][bn] = b1s;
    __syncthreads();

    if (kt + 1 < NT) {
      const int k0 = (kt + 1) * BK;
      a0s = *(const float4*)(Arow0 + k0);
      a1s = *(const float4*)(Arow1 + k0);
      b0s = *(const float4*)(Wrow0 + (size_t)k0 * F);
      b1s = *(const float4*)(Wrow1 + (size_t)k0 * F);
    }

#pragma unroll
    for (int k = 0; k < BK; k += 2) {
      float a0[8], a1[8];
      *(float4*)&a0[0] = *(const float4*)&As[k][ty * 8];
      *(float4*)&a0[4] = *(const float4*)&As[k][ty * 8 + 4];
      *(float4*)&a1[0] = *(const float4*)&As[k + 1][ty * 8];
      *(float4*)&a1[4] = *(const float4*)&As[k + 1][ty * 8 + 4];
      const float4 p0 = *(const float4*)&Bs[k][tx * 4];
      const float4 p1 = *(const float4*)&Bs[k][tx * 4 + 64];
      const float4 p2 = *(const float4*)&Bs[k + 1][tx * 4];
      const float4 p3 = *(const float4*)&Bs[k + 1][tx * 4 + 64];
      v2f b0[4], b1[4];
      b0[0] = (v2f){p0.x, p0.y};
      b0[1] = (v2f){p0.z, p0.w};
      b0[2] = (v2f){p1.x, p1.y};
      b0[3] = (v2f){p1.z, p1.w};
      b1[0] = (v2f){p2.x, p2.y};
      b1[1] = (v2f){p2.z, p2.w};
      b1[2] = (v2f){p3.x, p3.y};
      b1[3] = (v2f){p3.z, p3.w};
#pragma unroll
      for (int m = 0; m < 8; ++m) {
#pragma unroll
        for (int q = 0; q < 4; ++q) {
          const v2f s0 = a0[m] + b0[q];  // v_pk_add_f32
          const v2f s1 = a1[m] + b1[q];  // v_pk_add_f32
          acc[m][q].x = fmaxf(fmaxf(acc[m][q].x, s0.x), s1.x);  // v_max3_f32
          acc[m][q].y = fmaxf(fmaxf(acc[m][q].y, s0.y), s1.y);  // v_max3_f32
        }
      }
    }
    __syncthreads();
  }

  // epilogue: out = max(acc, bias[n])
  const float4 bv0 = *(const float4*)(bias + col0 + tx * 4);
  const float4 bv1 = *(const float4*)(bias + col0 + tx * 4 + 64);
#pragma unroll
  for (int m = 0; m < 8; ++m) {
    float* orow = out + (size_t)(row0 + ty * 8 + m) * F + col0 + tx * 4;
    float4 o0, o1;
    o0.x = fmaxf(acc[m][0].x, bv0.x);
    o0.y = fmaxf(acc[m][0].y, bv0.y);
    o0.z = fmaxf(acc[m][1].x, bv0.z);
    o0.w = fmaxf(acc[m][1].y, bv0.w);
    o1.x = fmaxf(acc[m][2].x, bv1.x);
    o1.y = fmaxf(acc[m][2].y, bv1.y);
    o1.z = fmaxf(acc[m][3].x, bv1.z);
    o1.w = fmaxf(acc[m][3].y, bv1.w);
    *(float4*)orow = o0;
    *(float4*)(orow + 64) = o1;
  }
}

extern "C" void kernel_launch(void* const* d_in, const int* in_sizes, int n_in,
                              void* d_out, int out_size, void* d_ws, size_t ws_size,
                              hipStream_t stream) {
  const float* x = (const float*)d_in[0];
  const float* Wm = (const float*)d_in[1];
  const float* bias = (const float*)d_in[2];
  const float* gamma = (const float*)d_in[3];
  const float* beta = (const float*)d_in[4];
  float* out = (float*)d_out;
  float* xn = (float*)d_ws;  // [B, F] f32 = 16 MB scratch

  const int Brows = in_sizes[0] / F;  // 4096

  ln_kernel<<<Brows / 4, 256, 0, stream>>>(x, gamma, beta, xn);

  dim3 grid(F / BN, Brows / BM);  // 8 x 32 = 256 blocks
  trop_kernel<<<grid, 256, 0, stream>>>(xn, Wm, bias, out);
}

// Round 3
// 232.615 us; speedup vs baseline: 1.2541x; 1.1234x over previous
//
#include <hip/hip_runtime.h>
#include <math.h>

#define F 1024
#define BM 128
#define BN 128
#define BK 16
#define NSPLIT 2

typedef float v2f __attribute__((ext_vector_type(2)));
typedef float v4f __attribute__((ext_vector_type(4)));

#define SHUF2(v, i, j) __builtin_shufflevector(v, v, i, j)

// d = {a.lo + b.lo, a.lo + b.hi}  (broadcast a.lo via op_sel, no v_mov)
static __device__ __forceinline__ v2f pk_add_blo(v2f a, v2f b) {
  v2f d;
  asm("v_pk_add_f32 %0, %1, %2 op_sel:[0,0] op_sel_hi:[0,1]"
      : "=v"(d) : "v"(a), "v"(b));
  return d;
}
// d = {a.hi + b.lo, a.hi + b.hi}  (broadcast a.hi)
static __device__ __forceinline__ v2f pk_add_bhi(v2f a, v2f b) {
  v2f d;
  asm("v_pk_add_f32 %0, %1, %2 op_sel:[1,0] op_sel_hi:[1,1]"
      : "=v"(d) : "v"(a), "v"(b));
  return d;
}
static __device__ __forceinline__ float fmax3(float a, float b, float c) {
  float d;
  asm("v_max3_f32 %0, %1, %2, %3" : "=v"(d) : "v"(a), "v"(b), "v"(c));
  return d;
}

// ---------------- LayerNorm: one WAVE per row ----------------
__global__ __launch_bounds__(256) void ln_kernel(const float* __restrict__ x,
                                                 const float* __restrict__ gamma,
                                                 const float* __restrict__ beta,
                                                 float* __restrict__ xn) {
  const int lane = threadIdx.x & 63;
  const int wv = threadIdx.x >> 6;
  const int row = blockIdx.x * 4 + wv;
  const float4* xr = (const float4*)(x + (size_t)row * F);
  float4 v[4];
  float s = 0.f;
#pragma unroll
  for (int j = 0; j < 4; ++j) {
    v[j] = xr[lane + 64 * j];
    s += v[j].x + v[j].y + v[j].z + v[j].w;
  }
#pragma unroll
  for (int off = 32; off; off >>= 1) s += __shfl_xor(s, off, 64);
  const float mu = s * (1.0f / F);
  float sq = 0.f;
#pragma unroll
  for (int j = 0; j < 4; ++j) {
    v[j].x -= mu; v[j].y -= mu; v[j].z -= mu; v[j].w -= mu;
    sq += v[j].x * v[j].x + v[j].y * v[j].y + v[j].z * v[j].z + v[j].w * v[j].w;
  }
#pragma unroll
  for (int off = 32; off; off >>= 1) sq += __shfl_xor(sq, off, 64);
  const float r = rsqrtf(sq * (1.0f / F) + 1e-5f);
  const float4* g4 = (const float4*)gamma;
  const float4* b4 = (const float4*)beta;
  float4* o = (float4*)(xn + (size_t)row * F);
#pragma unroll
  for (int j = 0; j < 4; ++j) {
    const int idx = lane + 64 * j;
    const float4 g = g4[idx];
    const float4 bb = b4[idx];
    float4 ov;
    ov.x = v[j].x * r * g.x + bb.x;
    ov.y = v[j].y * r * g.y + bb.y;
    ov.z = v[j].z * r * g.z + bb.z;
    ov.w = v[j].w * r * g.w + bb.w;
    o[idx] = ov;
  }
}

// ---------------- Tropical (max,+) GEMM, optional split-K ----------------
// Block (x,y,z): tile rows [128*y), cols [128*x), k-range z*ntiles*BK ..
// dst row-major [totrows, F]; z>0 writes to dst + z*totrows*F (partials).
__global__ __launch_bounds__(256) void trop_kernel(const float* __restrict__ A,
                                                   const float* __restrict__ Wm,
                                                   const float* __restrict__ bias,
                                                   float* __restrict__ dst,
                                                   int ntiles, int totrows, int fuse) {
  __shared__ float As[BK][BM + 4];  // transposed: As[k][m]
  __shared__ float Bs[BK][BN];

  const int tid = threadIdx.x;
  const int tx = tid & 15;
  const int ty = tid >> 4;
  const int row0 = blockIdx.y * BM;
  const int col0 = blockIdx.x * BN;
  const int kbase = blockIdx.z * ntiles * BK;

  const int am = tid >> 2;
  const int ak = (tid & 3) << 2;
  const int bk = tid >> 5;
  const int bn = (tid & 31) << 2;

  const float* Arow0 = A + (size_t)(row0 + am) * F + kbase + ak;
  const float* Arow1 = A + (size_t)(row0 + am + 64) * F + kbase + ak;
  const float* Wrow0 = Wm + (size_t)(kbase + bk) * F + col0 + bn;
  const float* Wrow1 = Wm + (size_t)(kbase + bk + 8) * F + col0 + bn;

  // acc[mp][p][q]: row = 8ty + 2mp + p, cols pair q: {4tx+2q,+1} (q<2), {64+4tx+2(q-2),+1}
  v2f acc[4][2][4];
#pragma unroll
  for (int mp = 0; mp < 4; ++mp)
#pragma unroll
    for (int p = 0; p < 2; ++p)
#pragma unroll
      for (int q = 0; q < 4; ++q) acc[mp][p][q] = (v2f)(-INFINITY);

  float4 a0s = *(const float4*)(Arow0);
  float4 a1s = *(const float4*)(Arow1);
  float4 b0s = *(const float4*)(Wrow0);
  float4 b1s = *(const float4*)(Wrow1);

  for (int kt = 0; kt < ntiles; ++kt) {
    As[ak + 0][am] = a0s.x;
    As[ak + 1][am] = a0s.y;
    As[ak + 2][am] = a0s.z;
    As[ak + 3][am] = a0s.w;
    As[ak + 0][am + 64] = a1s.x;
    As[ak + 1][am + 64] = a1s.y;
    As[ak + 2][am + 64] = a1s.z;
    As[ak + 3][am + 64] = a1s.w;
    *(float4*)&Bs[bk][bn] = b0s;
    *(float4*)&Bs[bk + 8][bn] = b1s;
    __syncthreads();

    if (kt + 1 < ntiles) {
      const int k0 = (kt + 1) * BK;
      a0s = *(const float4*)(Arow0 + k0);
      a1s = *(const float4*)(Arow1 + k0);
      b0s = *(const float4*)(Wrow0 + (size_t)k0 * F);
      b1s = *(const float4*)(Wrow1 + (size_t)k0 * F);
    }

#pragma unroll
    for (int k = 0; k < BK; k += 2) {
      const v4f fa0a = *(const v4f*)&As[k][ty * 8];
      const v4f fa0b = *(const v4f*)&As[k][ty * 8 + 4];
      const v4f fa1a = *(const v4f*)&As[k + 1][ty * 8];
      const v4f fa1b = *(const v4f*)&As[k + 1][ty * 8 + 4];
      const v4f fb0a = *(const v4f*)&Bs[k][tx * 4];
      const v4f fb0b = *(const v4f*)&Bs[k][tx * 4 + 64];
      const v4f fb1a = *(const v4f*)&Bs[k + 1][tx * 4];
      const v4f fb1b = *(const v4f*)&Bs[k + 1][tx * 4 + 64];
      v2f a0[4], a1[4], b0[4], b1[4];
      a0[0] = SHUF2(fa0a, 0, 1); a0[1] = SHUF2(fa0a, 2, 3);
      a0[2] = SHUF2(fa0b, 0, 1); a0[3] = SHUF2(fa0b, 2, 3);
      a1[0] = SHUF2(fa1a, 0, 1); a1[1] = SHUF2(fa1a, 2, 3);
      a1[2] = SHUF2(fa1b, 0, 1); a1[3] = SHUF2(fa1b, 2, 3);
      b0[0] = SHUF2(fb0a, 0, 1); b0[1] = SHUF2(fb0a, 2, 3);
      b0[2] = SHUF2(fb0b, 0, 1); b0[3] = SHUF2(fb0b, 2, 3);
      b1[0] = SHUF2(fb1a, 0, 1); b1[1] = SHUF2(fb1a, 2, 3);
      b1[2] = SHUF2(fb1b, 0, 1); b1[3] = SHUF2(fb1b, 2, 3);
#pragma unroll
      for (int mp = 0; mp < 4; ++mp) {
#pragma unroll
        for (int q = 0; q < 4; ++q) {
          // p = 0: broadcast a.lo ; p = 1: broadcast a.hi
          v2f s0 = pk_add_blo(a0[mp], b0[q]);
          v2f s1 = pk_add_blo(a1[mp], b1[q]);
          acc[mp][0][q].x = fmax3(acc[mp][0][q].x, s0.x, s1.x);
          acc[mp][0][q].y = fmax3(acc[mp][0][q].y, s0.y, s1.y);
          s0 = pk_add_bhi(a0[mp], b0[q]);
          s1 = pk_add_bhi(a1[mp], b1[q]);
          acc[mp][1][q].x = fmax3(acc[mp][1][q].x, s0.x, s1.x);
          acc[mp][1][q].y = fmax3(acc[mp][1][q].y, s0.y, s1.y);
        }
      }
    }
    __syncthreads();
  }

  float* base = dst + (size_t)blockIdx.z * totrows * F;
  float4 bv0, bv1;
  if (fuse) {
    bv0 = *(const float4*)(bias + col0 + tx * 4);
    bv1 = *(const float4*)(bias + col0 + tx * 4 + 64);
  }
#pragma unroll
  for (int mp = 0; mp < 4; ++mp) {
#pragma unroll
    for (int p = 0; p < 2; ++p) {
      float* orow = base + (size_t)(row0 + ty * 8 + 2 * mp + p) * F + col0 + tx * 4;
      float4 o0, o1;
      o0.x = acc[mp][p][0].x; o0.y = acc[mp][p][0].y;
      o0.z = acc[mp][p][1].x; o0.w = acc[mp][p][1].y;
      o1.x = acc[mp][p][2].x; o1.y = acc[mp][p][2].y;
      o1.z = acc[mp][p][3].x; o1.w = acc[mp][p][3].y;
      if (fuse) {
        o0.x = fmaxf(o0.x, bv0.x); o0.y = fmaxf(o0.y, bv0.y);
        o0.z = fmaxf(o0.z, bv0.z); o0.w = fmaxf(o0.w, bv0.w);
        o1.x = fmaxf(o1.x, bv1.x); o1.y = fmaxf(o1.y, bv1.y);
        o1.z = fmaxf(o1.z, bv1.z); o1.w = fmaxf(o1.w, bv1.w);
      }
      *(float4*)orow = o0;
      *(float4*)(orow + 64) = o1;
    }
  }
}

// ---------------- combine: out = max(p0, p1, bias) ----------------
__global__ __launch_bounds__(256) void combine_kernel(const float* __restrict__ p0,
                                                      const float* __restrict__ p1,
                                                      const float* __restrict__ bias,
                                                      float* __restrict__ out) {
  const int i = blockIdx.x * 256 + threadIdx.x;  // float4 index
  const v4f a = ((const v4f*)p0)[i];
  const v4f b = ((const v4f*)p1)[i];
  const v4f bv = ((const v4f*)bias)[i & (F / 4 - 1)];
  v4f o;
  o.x = fmax3(a.x, b.x, bv.x);
  o.y = fmax3(a.y, b.y, bv.y);
  o.z = fmax3(a.z, b.z, bv.z);
  o.w = fmax3(a.w, b.w, bv.w);
  ((v4f*)out)[i] = o;
}

extern "C" void kernel_launch(void* const* d_in, const int* in_sizes, int n_in,
                              void* d_out, int out_size, void* d_ws, size_t ws_size,
                              hipStream_t stream) {
  const float* x = (const float*)d_in[0];
  const float* Wm = (const float*)d_in[1];
  const float* bias = (const float*)d_in[2];
  const float* gamma = (const float*)d_in[3];
  const float* beta = (const float*)d_in[4];
  float* out = (float*)d_out;
  float* xn = (float*)d_ws;  // [B, F] f32 = 16 MB

  const int Brows = in_sizes[0] / F;  // 4096

  ln_kernel<<<Brows / 4, 256, 0, stream>>>(x, gamma, beta, xn);

  const size_t need = (size_t)(1 + NSPLIT) * Brows * F * sizeof(float);
  if (ws_size >= need) {
    // split-K: 2x blocks -> 2 blocks/CU, partials in ws
    float* part = xn + (size_t)Brows * F;
    dim3 grid(F / BN, Brows / BM, NSPLIT);
    trop_kernel<<<grid, 256, 0, stream>>>(xn, Wm, bias, part,
                                          (F / BK) / NSPLIT, Brows, 0);
    combine_kernel<<<(Brows * F) / 1024, 256, 0, stream>>>(
        part, part + (size_t)Brows * F, bias, out);
  } else {
    dim3 grid(F / BN, Brows / BM, 1);
    trop_kernel<<<grid, 256, 0, stream>>>(xn, Wm, bias, out, F / BK, Brows, 1);
  }
}

// Round 4
// 223.899 us; speedup vs baseline: 1.3030x; 1.0389x over previous
//
#include <hip/hip_runtime.h>
#include <math.h>

#define F 1024
#define BM 128
#define BN 128
#define BK 16

typedef float v2f __attribute__((ext_vector_type(2)));
typedef float v4f __attribute__((ext_vector_type(4)));

#define SHUF2(v, i, j) __builtin_shufflevector(v, v, i, j)

// d = {a.lo + b.lo, a.lo + b.hi}  (broadcast a.lo via op_sel)
static __device__ __forceinline__ v2f pk_add_blo(v2f a, v2f b) {
  v2f d;
  asm("v_pk_add_f32 %0, %1, %2 op_sel:[0,0] op_sel_hi:[0,1]"
      : "=v"(d) : "v"(a), "v"(b));
  return d;
}
// d = {a.hi + b.lo, a.hi + b.hi}  (broadcast a.hi)
static __device__ __forceinline__ v2f pk_add_bhi(v2f a, v2f b) {
  v2f d;
  asm("v_pk_add_f32 %0, %1, %2 op_sel:[1,0] op_sel_hi:[1,1]"
      : "=v"(d) : "v"(a), "v"(b));
  return d;
}
static __device__ __forceinline__ float fmax3(float a, float b, float c) {
  float d;
  asm("v_max3_f32 %0, %1, %2, %3" : "=v"(d) : "v"(a), "v"(b), "v"(c));
  return d;
}

// ---------------- LayerNorm: one WAVE per row ----------------
__global__ __launch_bounds__(256) void ln_kernel(const float* __restrict__ x,
                                                 const float* __restrict__ gamma,
                                                 const float* __restrict__ beta,
                                                 float* __restrict__ xn) {
  const int lane = threadIdx.x & 63;
  const int wv = threadIdx.x >> 6;
  const int row = blockIdx.x * 4 + wv;
  const float4* xr = (const float4*)(x + (size_t)row * F);
  float4 v[4];
  float s = 0.f;
#pragma unroll
  for (int j = 0; j < 4; ++j) {
    v[j] = xr[lane + 64 * j];
    s += v[j].x + v[j].y + v[j].z + v[j].w;
  }
#pragma unroll
  for (int off = 32; off; off >>= 1) s += __shfl_xor(s, off, 64);
  const float mu = s * (1.0f / F);
  float sq = 0.f;
#pragma unroll
  for (int j = 0; j < 4; ++j) {
    v[j].x -= mu; v[j].y -= mu; v[j].z -= mu; v[j].w -= mu;
    sq += v[j].x * v[j].x + v[j].y * v[j].y + v[j].z * v[j].z + v[j].w * v[j].w;
  }
#pragma unroll
  for (int off = 32; off; off >>= 1) sq += __shfl_xor(sq, off, 64);
  const float r = rsqrtf(sq * (1.0f / F) + 1e-5f);
  const float4* g4 = (const float4*)gamma;
  const float4* b4 = (const float4*)beta;
  float4* o = (float4*)(xn + (size_t)row * F);
#pragma unroll
  for (int j = 0; j < 4; ++j) {
    const int idx = lane + 64 * j;
    const float4 g = g4[idx];
    const float4 bb = b4[idx];
    float4 ov;
    ov.x = v[j].x * r * g.x + bb.x;
    ov.y = v[j].y * r * g.y + bb.y;
    ov.z = v[j].z * r * g.z + bb.z;
    ov.w = v[j].w * r * g.w + bb.w;
    o[idx] = ov;
  }
}

// ---------------- Tropical (max,+) GEMM, optional split-K ----------------
__global__ __launch_bounds__(256) void trop_kernel(const float* __restrict__ A,
                                                   const float* __restrict__ Wm,
                                                   const float* __restrict__ bias,
                                                   float* __restrict__ dst,
                                                   int ntiles, int totrows, int fuse) {
  __shared__ float As[BK][BM + 4];  // transposed: As[k][m]
  __shared__ float Bs[BK][BN];

  const int tid = threadIdx.x;
  const int tx = tid & 15;
  const int ty = tid >> 4;
  const int row0 = blockIdx.y * BM;
  const int col0 = blockIdx.x * BN;
  const int kbase = blockIdx.z * ntiles * BK;

  const int am = tid >> 2;
  const int ak = (tid & 3) << 2;
  const int bk = tid >> 5;
  const int bn = (tid & 31) << 2;

  const float* Arow0 = A + (size_t)(row0 + am) * F + kbase + ak;
  const float* Arow1 = A + (size_t)(row0 + am + 64) * F + kbase + ak;
  const float* Wrow0 = Wm + (size_t)(kbase + bk) * F + col0 + bn;
  const float* Wrow1 = Wm + (size_t)(kbase + bk + 8) * F + col0 + bn;

  v2f acc[4][2][4];
#pragma unroll
  for (int mp = 0; mp < 4; ++mp)
#pragma unroll
    for (int p = 0; p < 2; ++p)
#pragma unroll
      for (int q = 0; q < 4; ++q) acc[mp][p][q] = (v2f)(-INFINITY);

  float4 a0s = *(const float4*)(Arow0);
  float4 a1s = *(const float4*)(Arow1);
  float4 b0s = *(const float4*)(Wrow0);
  float4 b1s = *(const float4*)(Wrow1);

  for (int kt = 0; kt < ntiles; ++kt) {
    As[ak + 0][am] = a0s.x;
    As[ak + 1][am] = a0s.y;
    As[ak + 2][am] = a0s.z;
    As[ak + 3][am] = a0s.w;
    As[ak + 0][am + 64] = a1s.x;
    As[ak + 1][am + 64] = a1s.y;
    As[ak + 2][am + 64] = a1s.z;
    As[ak + 3][am + 64] = a1s.w;
    *(float4*)&Bs[bk][bn] = b0s;
    *(float4*)&Bs[bk + 8][bn] = b1s;
    __syncthreads();

    if (kt + 1 < ntiles) {
      const int k0 = (kt + 1) * BK;
      a0s = *(const float4*)(Arow0 + k0);
      a1s = *(const float4*)(Arow1 + k0);
      b0s = *(const float4*)(Wrow0 + (size_t)k0 * F);
      b1s = *(const float4*)(Wrow1 + (size_t)k0 * F);
    }

#pragma unroll
    for (int k = 0; k < BK; k += 2) {
      const v4f fa0a = *(const v4f*)&As[k][ty * 8];
      const v4f fa0b = *(const v4f*)&As[k][ty * 8 + 4];
      const v4f fa1a = *(const v4f*)&As[k + 1][ty * 8];
      const v4f fa1b = *(const v4f*)&As[k + 1][ty * 8 + 4];
      const v4f fb0a = *(const v4f*)&Bs[k][tx * 4];
      const v4f fb0b = *(const v4f*)&Bs[k][tx * 4 + 64];
      const v4f fb1a = *(const v4f*)&Bs[k + 1][tx * 4];
      const v4f fb1b = *(const v4f*)&Bs[k + 1][tx * 4 + 64];
      v2f a0[4], a1[4], b0[4], b1[4];
      a0[0] = SHUF2(fa0a, 0, 1); a0[1] = SHUF2(fa0a, 2, 3);
      a0[2] = SHUF2(fa0b, 0, 1); a0[3] = SHUF2(fa0b, 2, 3);
      a1[0] = SHUF2(fa1a, 0, 1); a1[1] = SHUF2(fa1a, 2, 3);
      a1[2] = SHUF2(fa1b, 0, 1); a1[3] = SHUF2(fa1b, 2, 3);
      b0[0] = SHUF2(fb0a, 0, 1); b0[1] = SHUF2(fb0a, 2, 3);
      b0[2] = SHUF2(fb0b, 0, 1); b0[3] = SHUF2(fb0b, 2, 3);
      b1[0] = SHUF2(fb1a, 0, 1); b1[1] = SHUF2(fb1a, 2, 3);
      b1[2] = SHUF2(fb1b, 0, 1); b1[3] = SHUF2(fb1b, 2, 3);
#pragma unroll
      for (int mp = 0; mp < 4; ++mp) {
#pragma unroll
        for (int q = 0; q < 4; ++q) {
          v2f s0 = pk_add_blo(a0[mp], b0[q]);
          v2f s1 = pk_add_blo(a1[mp], b1[q]);
          acc[mp][0][q].x = fmax3(acc[mp][0][q].x, s0.x, s1.x);
          acc[mp][0][q].y = fmax3(acc[mp][0][q].y, s0.y, s1.y);
          s0 = pk_add_bhi(a0[mp], b0[q]);
          s1 = pk_add_bhi(a1[mp], b1[q]);
          acc[mp][1][q].x = fmax3(acc[mp][1][q].x, s0.x, s1.x);
          acc[mp][1][q].y = fmax3(acc[mp][1][q].y, s0.y, s1.y);
        }
      }
    }
    __syncthreads();
  }

  float* base = dst + (size_t)blockIdx.z * totrows * F;
  float4 bv0, bv1;
  if (fuse) {
    bv0 = *(const float4*)(bias + col0 + tx * 4);
    bv1 = *(const float4*)(bias + col0 + tx * 4 + 64);
  }
#pragma unroll
  for (int mp = 0; mp < 4; ++mp) {
#pragma unroll
    for (int p = 0; p < 2; ++p) {
      float* orow = base + (size_t)(row0 + ty * 8 + 2 * mp + p) * F + col0 + tx * 4;
      float4 o0, o1;
      o0.x = acc[mp][p][0].x; o0.y = acc[mp][p][0].y;
      o0.z = acc[mp][p][1].x; o0.w = acc[mp][p][1].y;
      o1.x = acc[mp][p][2].x; o1.y = acc[mp][p][2].y;
      o1.z = acc[mp][p][3].x; o1.w = acc[mp][p][3].y;
      if (fuse) {
        o0.x = fmaxf(o0.x, bv0.x); o0.y = fmaxf(o0.y, bv0.y);
        o0.z = fmaxf(o0.z, bv0.z); o0.w = fmaxf(o0.w, bv0.w);
        o1.x = fmaxf(o1.x, bv1.x); o1.y = fmaxf(o1.y, bv1.y);
        o1.z = fmaxf(o1.z, bv1.z); o1.w = fmaxf(o1.w, bv1.w);
      }
      *(float4*)orow = o0;
      *(float4*)(orow + 64) = o1;
    }
  }
}

// ---------------- combine: out = max(partials..., bias) ----------------
__global__ __launch_bounds__(256) void combine2_kernel(const float* __restrict__ p,
                                                       size_t pstride,
                                                       const float* __restrict__ bias,
                                                       float* __restrict__ out) {
  const int i = blockIdx.x * 256 + threadIdx.x;
  const v4f a = ((const v4f*)p)[i];
  const v4f b = ((const v4f*)(p + pstride))[i];
  const v4f bv = ((const v4f*)bias)[i & (F / 4 - 1)];
  v4f o;
  o.x = fmax3(a.x, b.x, bv.x);
  o.y = fmax3(a.y, b.y, bv.y);
  o.z = fmax3(a.z, b.z, bv.z);
  o.w = fmax3(a.w, b.w, bv.w);
  ((v4f*)out)[i] = o;
}

__global__ __launch_bounds__(256) void combine4_kernel(const float* __restrict__ p,
                                                       size_t pstride,
                                                       const float* __restrict__ bias,
                                                       float* __restrict__ out) {
  const int i = blockIdx.x * 256 + threadIdx.x;
  const v4f a = ((const v4f*)p)[i];
  const v4f b = ((const v4f*)(p + pstride))[i];
  const v4f c = ((const v4f*)(p + 2 * pstride))[i];
  const v4f d = ((const v4f*)(p + 3 * pstride))[i];
  const v4f bv = ((const v4f*)bias)[i & (F / 4 - 1)];
  v4f o;
  o.x = fmax3(fmax3(a.x, b.x, c.x), d.x, bv.x);
  o.y = fmax3(fmax3(a.y, b.y, c.y), d.y, bv.y);
  o.z = fmax3(fmax3(a.z, b.z, c.z), d.z, bv.z);
  o.w = fmax3(fmax3(a.w, b.w, c.w), d.w, bv.w);
  ((v4f*)out)[i] = o;
}

extern "C" void kernel_launch(void* const* d_in, const int* in_sizes, int n_in,
                              void* d_out, int out_size, void* d_ws, size_t ws_size,
                              hipStream_t stream) {
  const float* x = (const float*)d_in[0];
  const float* Wm = (const float*)d_in[1];
  const float* bias = (const float*)d_in[2];
  const float* gamma = (const float*)d_in[3];
  const float* beta = (const float*)d_in[4];
  float* out = (float*)d_out;
  float* xn = (float*)d_ws;  // [B, F] f32 = 16 MB

  const int Brows = in_sizes[0] / F;  // 4096
  const size_t plane = (size_t)Brows * F;

  ln_kernel<<<Brows / 4, 256, 0, stream>>>(x, gamma, beta, xn);

  const size_t need4 = 5 * plane * sizeof(float);
  const size_t need2 = 3 * plane * sizeof(float);
  if (ws_size >= need4) {
    // split-K = 4: 1024 blocks -> 4 blocks/CU (4 waves/SIMD)
    float* part = xn + plane;
    dim3 grid(F / BN, Brows / BM, 4);
    trop_kernel<<<grid, 256, 0, stream>>>(xn, Wm, bias, part,
                                          (F / BK) / 4, Brows, 0);
    combine4_kernel<<<(Brows * F) / 1024, 256, 0, stream>>>(part, plane, bias, out);
  } else if (ws_size >= need2) {
    float* part = xn + plane;
    dim3 grid(F / BN, Brows / BM, 2);
    trop_kernel<<<grid, 256, 0, stream>>>(xn, Wm, bias, part,
                                          (F / BK) / 2, Brows, 0);
    combine2_kernel<<<(Brows * F) / 1024, 256, 0, stream>>>(part, plane, bias, out);
  } else {
    dim3 grid(F / BN, Brows / BM, 1);
    trop_kernel<<<grid, 256, 0, stream>>>(xn, Wm, bias, out, F / BK, Brows, 1);
  }
}

// Round 5
// 220.049 us; speedup vs baseline: 1.3258x; 1.0175x over previous
//
#include <hip/hip_runtime.h>
#include <math.h>

#define F 1024
#define BM 128
#define BN 128
#define BK 16

typedef _Float16 h2 __attribute__((ext_vector_type(2)));
typedef _Float16 h4 __attribute__((ext_vector_type(4)));
typedef _Float16 h8 __attribute__((ext_vector_type(8)));
typedef float v4f __attribute__((ext_vector_type(4)));

#define SHUF2(v, i, j) __builtin_shufflevector(v, v, i, j)
#define SHUF4(v, a, b, c, d) __builtin_shufflevector(v, v, a, b, c, d)

// d = {a.lo + b.lo, a.lo + b.hi}  (broadcast a.lo)
static __device__ __forceinline__ h2 pk_add_blo(h2 a, h2 b) {
  h2 d;
  asm("v_pk_add_f16 %0, %1, %2 op_sel:[0,0] op_sel_hi:[0,1]"
      : "=v"(d) : "v"(a), "v"(b));
  return d;
}
// d = {a.hi + b.lo, a.hi + b.hi}  (broadcast a.hi)
static __device__ __forceinline__ h2 pk_add_bhi(h2 a, h2 b) {
  h2 d;
  asm("v_pk_add_f16 %0, %1, %2 op_sel:[1,0] op_sel_hi:[1,1]"
      : "=v"(d) : "v"(a), "v"(b));
  return d;
}
static __device__ __forceinline__ h2 pk_max(h2 a, h2 b) {
  h2 d;
  asm("v_pk_max_f16 %0, %1, %2" : "=v"(d) : "v"(a), "v"(b));
  return d;
}
static __device__ __forceinline__ float fmax3(float a, float b, float c) {
  float d;
  asm("v_max3_f32 %0, %1, %2, %3" : "=v"(d) : "v"(a), "v"(b), "v"(c));
  return d;
}

// ---------------- LayerNorm: one WAVE per row, f32 compute, fp16 out ----------------
__global__ __launch_bounds__(256) void ln_kernel(const float* __restrict__ x,
                                                 const float* __restrict__ gamma,
                                                 const float* __restrict__ beta,
                                                 _Float16* __restrict__ xnh) {
  const int lane = threadIdx.x & 63;
  const int wv = threadIdx.x >> 6;
  const int row = blockIdx.x * 4 + wv;
  const float4* xr = (const float4*)(x + (size_t)row * F);
  float4 v[4];
  float s = 0.f;
#pragma unroll
  for (int j = 0; j < 4; ++j) {
    v[j] = xr[lane + 64 * j];
    s += v[j].x + v[j].y + v[j].z + v[j].w;
  }
#pragma unroll
  for (int off = 32; off; off >>= 1) s += __shfl_xor(s, off, 64);
  const float mu = s * (1.0f / F);
  float sq = 0.f;
#pragma unroll
  for (int j = 0; j < 4; ++j) {
    v[j].x -= mu; v[j].y -= mu; v[j].z -= mu; v[j].w -= mu;
    sq += v[j].x * v[j].x + v[j].y * v[j].y + v[j].z * v[j].z + v[j].w * v[j].w;
  }
#pragma unroll
  for (int off = 32; off; off >>= 1) sq += __shfl_xor(sq, off, 64);
  const float r = rsqrtf(sq * (1.0f / F) + 1e-5f);
  const float4* g4 = (const float4*)gamma;
  const float4* b4 = (const float4*)beta;
  h4* o = (h4*)(xnh + (size_t)row * F);
#pragma unroll
  for (int j = 0; j < 4; ++j) {
    const int idx = lane + 64 * j;
    const float4 g = g4[idx];
    const float4 bb = b4[idx];
    h4 ov = {(_Float16)(v[j].x * r * g.x + bb.x),
             (_Float16)(v[j].y * r * g.y + bb.y),
             (_Float16)(v[j].z * r * g.z + bb.z),
             (_Float16)(v[j].w * r * g.w + bb.w)};
    o[idx] = ov;
  }
}

// ---------------- f32 -> fp16 convert (for W) ----------------
__global__ __launch_bounds__(256) void cvt_kernel(const float* __restrict__ in,
                                                  _Float16* __restrict__ out) {
  const int i = blockIdx.x * 256 + threadIdx.x;  // one float4 -> h4
  const v4f v = ((const v4f*)in)[i];
  h4 o = {(_Float16)v.x, (_Float16)v.y, (_Float16)v.z, (_Float16)v.w};
  ((h4*)out)[i] = o;
}

// ---------------- fp16 tropical (max,+) GEMM, split-K ----------------
// out[m,n] = max_k A[m,k]+W[k,n]. Thread (tx,ty): rows 8ty..+7, cols 8tx..+7.
// As is k-major per row (no transpose in staging); A frag read amortized 4 k / b64.
__global__ __launch_bounds__(256) void trop_h(const _Float16* __restrict__ A,
                                              const _Float16* __restrict__ Wh,
                                              const float* __restrict__ bias,
                                              _Float16* __restrict__ dsth,
                                              float* __restrict__ outf,
                                              int ntiles, int totrows, int fuse) {
  __shared__ _Float16 As[BM][BK + 4];  // row stride 40B: b64-aligned, 2-way banks
  __shared__ _Float16 Bs[BK][BN];

  const int tid = threadIdx.x;
  const int tx = tid & 15;
  const int ty = tid >> 4;
  const int row0 = blockIdx.y * BM;
  const int col0 = blockIdx.x * BN;
  const int kbase = blockIdx.z * ntiles * BK;

  const int am2 = tid >> 1, aj = tid & 1;   // A stage: row am2, k-half aj
  const int bi = tid >> 4, bj = tid & 15;   // B stage: k-row bi, col-group bj

  const _Float16* Asrc = A + (size_t)(row0 + am2) * F + kbase + aj * 8;
  const _Float16* Bsrc = Wh + (size_t)(kbase + bi) * F + col0 + bj * 8;

  const _Float16 NEG = (_Float16)(-60000.0f);
  h2 acc[8][4];
#pragma unroll
  for (int m = 0; m < 8; ++m)
#pragma unroll
    for (int np = 0; np < 4; ++np) acc[m][np] = (h2){NEG, NEG};

  h8 a_st = *(const h8*)Asrc;
  h8 b_st = *(const h8*)Bsrc;

  for (int kt = 0; kt < ntiles; ++kt) {
    *(h4*)&As[am2][aj * 8] = SHUF4(a_st, 0, 1, 2, 3);
    *(h4*)&As[am2][aj * 8 + 4] = SHUF4(a_st, 4, 5, 6, 7);
    *(h8*)&Bs[bi][bj * 8] = b_st;
    __syncthreads();

    if (kt + 1 < ntiles) {
      a_st = *(const h8*)(Asrc + (kt + 1) * BK);
      b_st = *(const h8*)(Bsrc + (size_t)(kt + 1) * BK * F);
    }

#pragma unroll
    for (int kq = 0; kq < 4; ++kq) {
      h4 a4[8];
#pragma unroll
      for (int m = 0; m < 8; ++m) a4[m] = *(const h4*)&As[ty * 8 + m][kq * 4];
#pragma unroll
      for (int kp = 0; kp < 2; ++kp) {
        const int k = kq * 4 + kp * 2;
        const h8 bA = *(const h8*)&Bs[k][tx * 8];
        const h8 bB = *(const h8*)&Bs[k + 1][tx * 8];
        h2 b0[4], b1[4];
        b0[0] = SHUF2(bA, 0, 1); b0[1] = SHUF2(bA, 2, 3);
        b0[2] = SHUF2(bA, 4, 5); b0[3] = SHUF2(bA, 6, 7);
        b1[0] = SHUF2(bB, 0, 1); b1[1] = SHUF2(bB, 2, 3);
        b1[2] = SHUF2(bB, 4, 5); b1[3] = SHUF2(bB, 6, 7);
#pragma unroll
        for (int m = 0; m < 8; ++m) {
          const h2 a = kp ? SHUF2(a4[m], 2, 3) : SHUF2(a4[m], 0, 1);
#pragma unroll
          for (int np = 0; np < 4; ++np) {
            const h2 s0 = pk_add_blo(a, b0[np]);  // a[k]   + {b,b'}
            const h2 s1 = pk_add_bhi(a, b1[np]);  // a[k+1] + {b,b'}
            acc[m][np] = pk_max(acc[m][np], pk_max(s0, s1));
          }
        }
      }
    }
    __syncthreads();
  }

  if (fuse) {
    const float4 bv0 = *(const float4*)(bias + col0 + tx * 8);
    const float4 bv1 = *(const float4*)(bias + col0 + tx * 8 + 4);
#pragma unroll
    for (int m = 0; m < 8; ++m) {
      float* orow = outf + (size_t)(row0 + ty * 8 + m) * F + col0 + tx * 8;
      float4 o0, o1;
      o0.x = fmaxf((float)acc[m][0].x, bv0.x);
      o0.y = fmaxf((float)acc[m][0].y, bv0.y);
      o0.z = fmaxf((float)acc[m][1].x, bv0.z);
      o0.w = fmaxf((float)acc[m][1].y, bv0.w);
      o1.x = fmaxf((float)acc[m][2].x, bv1.x);
      o1.y = fmaxf((float)acc[m][2].y, bv1.y);
      o1.z = fmaxf((float)acc[m][3].x, bv1.z);
      o1.w = fmaxf((float)acc[m][3].y, bv1.w);
      *(float4*)orow = o0;
      *(float4*)(orow + 4) = o1;
    }
  } else {
    _Float16* base = dsth + (size_t)blockIdx.z * totrows * F;
#pragma unroll
    for (int m = 0; m < 8; ++m) {
      h8 ov = {acc[m][0].x, acc[m][0].y, acc[m][1].x, acc[m][1].y,
               acc[m][2].x, acc[m][2].y, acc[m][3].x, acc[m][3].y};
      *(h8*)(base + (size_t)(row0 + ty * 8 + m) * F + col0 + tx * 8) = ov;
    }
  }
}

// ---------------- combine: out = max(4 fp16 partials, bias) in f32 ----------------
__global__ __launch_bounds__(256) void combine4h(const _Float16* __restrict__ p,
                                                 size_t plane,
                                                 const float* __restrict__ bias,
                                                 float* __restrict__ out) {
  const int i = blockIdx.x * 256 + threadIdx.x;  // h8 index
  const h8 a = ((const h8*)p)[i];
  const h8 b = ((const h8*)(p + plane))[i];
  const h8 c = ((const h8*)(p + 2 * plane))[i];
  const h8 d = ((const h8*)(p + 3 * plane))[i];
  const int nb = (i & (F / 8 - 1)) * 8;
  float4* o4 = (float4*)(out + (size_t)i * 8);
  float4 o0, o1;
  o0.x = fmaxf(fmax3(fmaxf((float)a[0], (float)b[0]), (float)c[0], (float)d[0]), bias[nb + 0]);
  o0.y = fmaxf(fmax3(fmaxf((float)a[1], (float)b[1]), (float)c[1], (float)d[1]), bias[nb + 1]);
  o0.z = fmaxf(fmax3(fmaxf((float)a[2], (float)b[2]), (float)c[2], (float)d[2]), bias[nb + 2]);
  o0.w = fmaxf(fmax3(fmaxf((float)a[3], (float)b[3]), (float)c[3], (float)d[3]), bias[nb + 3]);
  o1.x = fmaxf(fmax3(fmaxf((float)a[4], (float)b[4]), (float)c[4], (float)d[4]), bias[nb + 4]);
  o1.y = fmaxf(fmax3(fmaxf((float)a[5], (float)b[5]), (float)c[5], (float)d[5]), bias[nb + 5]);
  o1.z = fmaxf(fmax3(fmaxf((float)a[6], (float)b[6]), (float)c[6], (float)d[6]), bias[nb + 6]);
  o1.w = fmaxf(fmax3(fmaxf((float)a[7], (float)b[7]), (float)c[7], (float)d[7]), bias[nb + 7]);
  o4[0] = o0;
  o4[1] = o1;
}

extern "C" void kernel_launch(void* const* d_in, const int* in_sizes, int n_in,
                              void* d_out, int out_size, void* d_ws, size_t ws_size,
                              hipStream_t stream) {
  const float* x = (const float*)d_in[0];
  const float* Wm = (const float*)d_in[1];
  const float* bias = (const float*)d_in[2];
  const float* gamma = (const float*)d_in[3];
  const float* beta = (const float*)d_in[4];
  float* out = (float*)d_out;

  const int Brows = in_sizes[0] / F;  // 4096
  const size_t plane = (size_t)Brows * F;

  _Float16* xnh = (_Float16*)d_ws;              // plane halves (8 MB)
  _Float16* Wh = xnh + plane;                   // F*F halves (2 MB)
  _Float16* parts = Wh + (size_t)F * F;         // 4 planes halves (32 MB)

  ln_kernel<<<Brows / 4, 256, 0, stream>>>(x, gamma, beta, xnh);
  cvt_kernel<<<(F * F) / 1024, 256, 0, stream>>>(Wm, Wh);

  const size_t need4 = (5 * plane + (size_t)F * F) * sizeof(_Float16);
  const size_t need1 = (plane + (size_t)F * F) * sizeof(_Float16);
  if (ws_size >= need4) {
    dim3 grid(F / BN, Brows / BM, 4);  // 1024 blocks = 4 blocks/CU
    trop_h<<<grid, 256, 0, stream>>>(xnh, Wh, bias, parts, nullptr,
                                     (F / BK) / 4, Brows, 0);
    combine4h<<<(int)(plane / 2048), 256, 0, stream>>>(parts, plane, bias, out);
  } else if (ws_size >= need1) {
    dim3 grid(F / BN, Brows / BM, 1);
    trop_h<<<grid, 256, 0, stream>>>(xnh, Wh, bias, nullptr, out, F / BK, Brows, 1);
  }
}

// Round 8
// 219.814 us; speedup vs baseline: 1.3272x; 1.0011x over previous
//
#include <hip/hip_runtime.h>
#include <math.h>

#define F 1024
#define BM 128
#define BN 128
#define BK 16

typedef _Float16 h2 __attribute__((ext_vector_type(2)));
typedef _Float16 h4 __attribute__((ext_vector_type(4)));
typedef _Float16 h8 __attribute__((ext_vector_type(8)));
typedef float v4f __attribute__((ext_vector_type(4)));

#define SHUF2(v, i, j) __builtin_shufflevector(v, v, i, j)
#define SHUF4(v, a, b, c, d) __builtin_shufflevector(v, v, a, b, c, d)

// VOP3P with op_sel broadcast — syntax bench-proven in R5.
static __device__ __forceinline__ h2 pk_add_blo(h2 a, h2 b) {
  h2 d;
  asm("v_pk_add_f16 %0, %1, %2 op_sel:[0,0] op_sel_hi:[0,1]"
      : "=v"(d) : "v"(a), "v"(b));
  return d;
}
static __device__ __forceinline__ h2 pk_add_bhi(h2 a, h2 b) {
  h2 d;
  asm("v_pk_add_f16 %0, %1, %2 op_sel:[1,0] op_sel_hi:[1,1]"
      : "=v"(d) : "v"(a), "v"(b));
  return d;
}
static __device__ __forceinline__ h2 pk_max(h2 a, h2 b) {
  h2 d;
  asm("v_pk_max_f16 %0, %1, %2" : "=v"(d) : "v"(a), "v"(b));
  return d;
}

// ---------------- LayerNorm: one WAVE per row, f32 compute, fp16 out ----------------
__global__ __launch_bounds__(256) void ln_kernel(const float* __restrict__ x,
                                                 const float* __restrict__ gamma,
                                                 const float* __restrict__ beta,
                                                 _Float16* __restrict__ xnh) {
  const int lane = threadIdx.x & 63;
  const int wv = threadIdx.x >> 6;
  const int row = blockIdx.x * 4 + wv;
  const float4* xr = (const float4*)(x + (size_t)row * F);
  float4 v[4];
  float s = 0.f;
#pragma unroll
  for (int j = 0; j < 4; ++j) {
    v[j] = xr[lane + 64 * j];
    s += v[j].x + v[j].y + v[j].z + v[j].w;
  }
#pragma unroll
  for (int off = 32; off; off >>= 1) s += __shfl_xor(s, off, 64);
  const float mu = s * (1.0f / F);
  float sq = 0.f;
#pragma unroll
  for (int j = 0; j < 4; ++j) {
    v[j].x -= mu; v[j].y -= mu; v[j].z -= mu; v[j].w -= mu;
    sq += v[j].x * v[j].x + v[j].y * v[j].y + v[j].z * v[j].z + v[j].w * v[j].w;
  }
#pragma unroll
  for (int off = 32; off; off >>= 1) sq += __shfl_xor(sq, off, 64);
  const float r = rsqrtf(sq * (1.0f / F) + 1e-5f);
  const float4* g4 = (const float4*)gamma;
  const float4* b4 = (const float4*)beta;
  h4* o = (h4*)(xnh + (size_t)row * F);
#pragma unroll
  for (int j = 0; j < 4; ++j) {
    const int idx = lane + 64 * j;
    const float4 g = g4[idx];
    const float4 bb = b4[idx];
    h4 ov = {(_Float16)(v[j].x * r * g.x + bb.x),
             (_Float16)(v[j].y * r * g.y + bb.y),
             (_Float16)(v[j].z * r * g.z + bb.z),
             (_Float16)(v[j].w * r * g.w + bb.w)};
    o[idx] = ov;
  }
}

// ---------------- f32 -> fp16 convert (for W) ----------------
__global__ __launch_bounds__(256) void cvt_kernel(const float* __restrict__ in,
                                                  _Float16* __restrict__ out) {
  const int i = blockIdx.x * 256 + threadIdx.x;
  const v4f v = ((const v4f*)in)[i];
  h4 o = {(_Float16)v.x, (_Float16)v.y, (_Float16)v.z, (_Float16)v.w};
  ((h4*)out)[i] = o;
}

// ---------------- fp16 tropical (max,+) GEMM, split-K ----------------
// Inner mix (R5-proven): 1 VOP3P per accumulator update.
__global__ __launch_bounds__(256) void trop_h(const _Float16* __restrict__ A,
                                              const _Float16* __restrict__ Wh,
                                              const float* __restrict__ bias,
                                              _Float16* __restrict__ dsth,
                                              float* __restrict__ outf,
                                              int ntiles, int totrows, int fuse) {
  __shared__ _Float16 As[BM][BK + 4];  // row stride 40B
  __shared__ _Float16 Bs[BK][BN];

  const int tid = threadIdx.x;
  const int tx = tid & 15;
  const int ty = tid >> 4;
  const int row0 = blockIdx.y * BM;
  const int col0 = blockIdx.x * BN;
  const int kbase = blockIdx.z * ntiles * BK;

  const int am2 = tid >> 1, aj = tid & 1;
  const int bi = tid >> 4, bj = tid & 15;

  const _Float16* Asrc = A + (size_t)(row0 + am2) * F + kbase + aj * 8;
  const _Float16* Bsrc = Wh + (size_t)(kbase + bi) * F + col0 + bj * 8;

  const _Float16 NEG = (_Float16)(-60000.0f);
  h2 acc[8][4];
#pragma unroll
  for (int m = 0; m < 8; ++m)
#pragma unroll
    for (int np = 0; np < 4; ++np) acc[m][np] = (h2){NEG, NEG};

  h8 a_st = *(const h8*)Asrc;
  h8 b_st = *(const h8*)Bsrc;

  for (int kt = 0; kt < ntiles; ++kt) {
    *(h4*)&As[am2][aj * 8] = SHUF4(a_st, 0, 1, 2, 3);
    *(h4*)&As[am2][aj * 8 + 4] = SHUF4(a_st, 4, 5, 6, 7);
    *(h8*)&Bs[bi][bj * 8] = b_st;
    __syncthreads();

    if (kt + 1 < ntiles) {
      a_st = *(const h8*)(Asrc + (kt + 1) * BK);
      b_st = *(const h8*)(Bsrc + (size_t)(kt + 1) * BK * F);
    }

#pragma unroll
    for (int kq = 0; kq < 4; ++kq) {
      h4 a4[8];
#pragma unroll
      for (int m = 0; m < 8; ++m) a4[m] = *(const h4*)&As[ty * 8 + m][kq * 4];
#pragma unroll
      for (int kp = 0; kp < 2; ++kp) {
        const int k = kq * 4 + kp * 2;
        const h8 bA = *(const h8*)&Bs[k][tx * 8];
        const h8 bB = *(const h8*)&Bs[k + 1][tx * 8];
        h2 b0[4], b1[4];
        b0[0] = SHUF2(bA, 0, 1); b0[1] = SHUF2(bA, 2, 3);
        b0[2] = SHUF2(bA, 4, 5); b0[3] = SHUF2(bA, 6, 7);
        b1[0] = SHUF2(bB, 0, 1); b1[1] = SHUF2(bB, 2, 3);
        b1[2] = SHUF2(bB, 4, 5); b1[3] = SHUF2(bB, 6, 7);
#pragma unroll
        for (int m = 0; m < 8; ++m) {
          const h2 a = kp ? SHUF2(a4[m], 2, 3) : SHUF2(a4[m], 0, 1);
#pragma unroll
          for (int np = 0; np < 4; ++np) {
            const h2 s0 = pk_add_blo(a, b0[np]);  // a_k   + {b_k(n), b_k(n1)}
            const h2 s1 = pk_add_bhi(a, b1[np]);  // a_k1  + {b_k1(n), b_k1(n1)}
            acc[m][np] = pk_max(acc[m][np], pk_max(s0, s1));
          }
        }
      }
    }
    __syncthreads();
  }

  if (fuse) {
    const float4 bv0 = *(const float4*)(bias + col0 + tx * 8);
    const float4 bv1 = *(const float4*)(bias + col0 + tx * 8 + 4);
#pragma unroll
    for (int m = 0; m < 8; ++m) {
      float* orow = outf + (size_t)(row0 + ty * 8 + m) * F + col0 + tx * 8;
      float4 o0, o1;
      o0.x = fmaxf((float)acc[m][0].x, bv0.x);
      o0.y = fmaxf((float)acc[m][0].y, bv0.y);
      o0.z = fmaxf((float)acc[m][1].x, bv0.z);
      o0.w = fmaxf((float)acc[m][1].y, bv0.w);
      o1.x = fmaxf((float)acc[m][2].x, bv1.x);
      o1.y = fmaxf((float)acc[m][2].y, bv1.y);
      o1.z = fmaxf((float)acc[m][3].x, bv1.z);
      o1.w = fmaxf((float)acc[m][3].y, bv1.w);
      *(float4*)orow = o0;
      *(float4*)(orow + 4) = o1;
    }
  } else {
    _Float16* base = dsth + (size_t)blockIdx.z * totrows * F;
#pragma unroll
    for (int m = 0; m < 8; ++m) {
      h8 ov = {acc[m][0].x, acc[m][0].y, acc[m][1].x, acc[m][1].y,
               acc[m][2].x, acc[m][2].y, acc[m][3].x, acc[m][3].y};
      *(h8*)(base + (size_t)(row0 + ty * 8 + m) * F + col0 + tx * 8) = ov;
    }
  }
}

// ---------------- combine: out = max(NP fp16 partials, bias) in f32 ----------------
template <int NP>
__global__ __launch_bounds__(256) void combineNh(const _Float16* __restrict__ p,
                                                 size_t plane,
                                                 const float* __restrict__ bias,
                                                 float* __restrict__ out) {
  const int i = blockIdx.x * 256 + threadIdx.x;  // h8 index
  h8 v = ((const h8*)p)[i];
  h2* vv = (h2*)&v;
#pragma unroll
  for (int q = 1; q < NP; ++q) {
    const h8 u = ((const h8*)(p + (size_t)q * plane))[i];
    const h2* uu = (const h2*)&u;
#pragma unroll
    for (int j = 0; j < 4; ++j) vv[j] = pk_max(vv[j], uu[j]);
  }
  const int nb = (i & (F / 8 - 1)) * 8;
  const v4f bb0 = *(const v4f*)(bias + nb);
  const v4f bb1 = *(const v4f*)(bias + nb + 4);
  float4* o4 = (float4*)(out + (size_t)i * 8);
  float4 o0, o1;
  o0.x = fmaxf((float)v[0], bb0.x);
  o0.y = fmaxf((float)v[1], bb0.y);
  o0.z = fmaxf((float)v[2], bb0.z);
  o0.w = fmaxf((float)v[3], bb0.w);
  o1.x = fmaxf((float)v[4], bb1.x);
  o1.y = fmaxf((float)v[5], bb1.y);
  o1.z = fmaxf((float)v[6], bb1.z);
  o1.w = fmaxf((float)v[7], bb1.w);
  o4[0] = o0;
  o4[1] = o1;
}

extern "C" void kernel_launch(void* const* d_in, const int* in_sizes, int n_in,
                              void* d_out, int out_size, void* d_ws, size_t ws_size,
                              hipStream_t stream) {
  const float* x = (const float*)d_in[0];
  const float* Wm = (const float*)d_in[1];
  const float* bias = (const float*)d_in[2];
  const float* gamma = (const float*)d_in[3];
  const float* beta = (const float*)d_in[4];
  float* out = (float*)d_out;

  const int Brows = in_sizes[0] / F;  // 4096
  const size_t plane = (size_t)Brows * F;

  _Float16* xnh = (_Float16*)d_ws;       // plane halves
  _Float16* Wh = xnh + plane;            // F*F halves
  _Float16* parts = Wh + (size_t)F * F;  // up to 8 planes halves

  ln_kernel<<<Brows / 4, 256, 0, stream>>>(x, gamma, beta, xnh);
  cvt_kernel<<<(F * F) / 1024, 256, 0, stream>>>(Wm, Wh);

  const size_t need8 = (9 * plane + (size_t)F * F) * sizeof(_Float16);
  const size_t need4 = (5 * plane + (size_t)F * F) * sizeof(_Float16);
  const size_t need1 = (plane + (size_t)F * F) * sizeof(_Float16);
  if (ws_size >= need8) {
    dim3 grid(F / BN, Brows / BM, 8);  // 2048 blocks = 8 blocks/CU
    trop_h<<<grid, 256, 0, stream>>>(xnh, Wh, bias, parts, nullptr,
                                     (F / BK) / 8, Brows, 0);
    combineNh<8><<<(int)(plane / 2048), 256, 0, stream>>>(parts, plane, bias, out);
  } else if (ws_size >= need4) {
    dim3 grid(F / BN, Brows / BM, 4);
    trop_h<<<grid, 256, 0, stream>>>(xnh, Wh, bias, parts, nullptr,
                                     (F / BK) / 4, Brows, 0);
    combineNh<4><<<(int)(plane / 2048), 256, 0, stream>>>(parts, plane, bias, out);
  } else if (ws_size >= need1) {
    dim3 grid(F / BN, Brows / BM, 1);
    trop_h<<<grid, 256, 0, stream>>>(xnh, Wh, bias, nullptr, out, F / BK, Brows, 1);
  }
}